// Round 1
// 565.379 us; speedup vs baseline: 1.1130x; 1.1130x over previous
//
#include <hip/hip_runtime.h>
#include <math.h>

// Problem constants
#define NROWS 32768       // B*H*W
#define KCODES 1024
#define DDIM 256
#define BM 32             // rows per block
#define QUANT_OFF 1                    // out offsets: loss@0, quant@1
#define PERP_OFF  8388609
#define ENC_OFF   8388610

// ws layout (floats): [0,1024) e2 norms, [1024,2048) counts, [2048] kld_sum, [2049] elat_sum

__global__ void __launch_bounds__(256)
vq_setup(const float* __restrict__ emb, float* __restrict__ ws) {
    int k = blockIdx.x * 256 + threadIdx.x;
    if (k < KCODES) {
        const float* row = emb + (size_t)k * DDIM;
        float s = 0.f;
        #pragma unroll 4
        for (int c = 0; c < DDIM; c += 4) {
            float4 v = *(const float4*)(row + c);
            s = fmaf(v.x, v.x, s); s = fmaf(v.y, v.y, s);
            s = fmaf(v.z, v.z, s); s = fmaf(v.w, v.w, s);
        }
        ws[k] = s;
        ws[KCODES + k] = 0.f;
        if (k == 0) { ws[2 * KCODES] = 0.f; ws[2 * KCODES + 1] = 0.f; }
    }
}

// load emb chunk (kc,dc) into staging regs: 4 codes per thread (sc0+64t), d-quad sd4
#define LDG(KC, DC) do { \
    const float* lp_ = emb + ((size_t)(((KC) << 8) + sc0) << 8) + ((DC) << 4) + (sd4 << 2); \
    g0 = *(const float4*)(lp_);          \
    g1 = *(const float4*)(lp_ + 16384);  \
    g2 = *(const float4*)(lp_ + 32768);  \
    g3 = *(const float4*)(lp_ + 49152);  \
} while (0)

__global__ void __launch_bounds__(256, 2)
vq_main(const float* __restrict__ inp, const float* __restrict__ emb,
        const float* __restrict__ gmb, float* __restrict__ out,
        float* __restrict__ ws) {
    // LDS: x tile transposed [d][row] (pad 36: float4 row reads stay aligned+broadcast),
    //      es double-buffered [2][16 d][264] — row stride 264 floats keeps the per-lane
    //      contiguous float4 code-quad reads 16B-aligned and bank-conflict-free.
    __shared__ float xs[DDIM][BM + 4];     // 36.9 KB
    __shared__ float es[2][16][264];       // 33.8 KB
    __shared__ float xn2p[8][BM];
    __shared__ float xn2[BM];
    __shared__ int   idxs[BM];
    __shared__ float redK[4], redE[4];

    const int tid = threadIdx.x;
    const int ct  = tid & 31;   // col-thread 0..31 (owns code quads ct*4 and 128+ct*4)
    const int rt  = tid >> 5;   // row-thread 0..7 (owns rows rt*4..rt*4+3)
    const int n0  = blockIdx.x * BM;
    const int b   = n0 >> 10;   // HW = 1024, block never straddles b
    const int s0  = n0 & 1023;
    const int sc0 = tid >> 2;   // staging: code base 0..63
    const int sd4 = tid & 3;    // staging: which d-quad of the 16-float slice

    const float* e2     = ws;
    float*       counts = ws + KCODES;

    // prefetch first es chunk (kc=0, dc=0) before anything else
    float4 g0, g1, g2, g3;
    LDG(0, 0);

    // ---- stage x tile: inputs[b][c][s0+r] -> xs[c][r] (coalesced global, conflict-free LDS)
    {
        const float* base = inp + ((size_t)b * DDIM) * 1024 + s0;
        for (int t = tid; t < DDIM * BM; t += 256) {
            int r = t & 31, c = t >> 5;
            xs[c][r] = base[(size_t)c * 1024 + r];
        }
    }
    __syncthreads();
    // ---- per-row squared norms
    {
        int r = tid & 31, p = tid >> 5;
        float s = 0.f;
        #pragma unroll 4
        for (int d = p * 32; d < p * 32 + 32; ++d) s = fmaf(xs[d][r], xs[d][r], s);
        xn2p[p][r] = s;
    }
    __syncthreads();
    if (tid < BM) {
        float s = 0.f;
        #pragma unroll
        for (int p = 0; p < 8; ++p) s += xn2p[p][tid];
        xn2[tid] = s;
    }
    // (first barrier inside the dc loop publishes xn2 before first epilogue use)

    float kld_acc = 0.f;
    float runval[4];
    int   runidx[4];
    #pragma unroll
    for (int r = 0; r < 4; ++r) { runval[r] = -1e30f; runidx[r] = 0; }

    // ---- main loop: 4 kc chunks of 256 codes; D in 16-wide double-buffered slices
    for (int kc = 0; kc < 4; ++kc) {
        const int kbase = kc * 256;
        float acc[4][8];
        #pragma unroll
        for (int r = 0; r < 4; ++r)
            #pragma unroll
            for (int j = 0; j < 8; ++j) acc[r][j] = 0.f;

        float4 gpre[8];          // gumbel prefetch: [row r][quad q]
        float4 e2a, e2b;         // e2 prefetch for this kc

        #pragma unroll 1
        for (int dc = 0; dc < 16; ++dc) {
            const int buf = dc & 1;
            // publish the prefetched chunk: es[buf][sd4*4+k][code]
            {
                const int dr = sd4 * 4;
                es[buf][dr + 0][sc0      ] = g0.x;
                es[buf][dr + 1][sc0      ] = g0.y;
                es[buf][dr + 2][sc0      ] = g0.z;
                es[buf][dr + 3][sc0      ] = g0.w;
                es[buf][dr + 0][sc0 +  64] = g1.x;
                es[buf][dr + 1][sc0 +  64] = g1.y;
                es[buf][dr + 2][sc0 +  64] = g1.z;
                es[buf][dr + 3][sc0 +  64] = g1.w;
                es[buf][dr + 0][sc0 + 128] = g2.x;
                es[buf][dr + 1][sc0 + 128] = g2.y;
                es[buf][dr + 2][sc0 + 128] = g2.z;
                es[buf][dr + 3][sc0 + 128] = g2.w;
                es[buf][dr + 0][sc0 + 192] = g3.x;
                es[buf][dr + 1][sc0 + 192] = g3.y;
                es[buf][dr + 2][sc0 + 192] = g3.z;
                es[buf][dr + 3][sc0 + 192] = g3.w;
            }
            __syncthreads();   // single barrier per dc: next store targets buf^1, safe

            // issue next chunk's global loads — latency hides under this dc's compute
            {
                int step = kc * 16 + dc + 1;
                if (step < 64) LDG(step >> 4, step & 15);
            }
            // prefetch gumbel + e2 for this kc's epilogue (consumed ~7 dc later)
            if (dc == 8) {
                const float* gb = gmb + ((size_t)(n0 + rt * 4) << 10) + kbase + ct * 4;
                #pragma unroll
                for (int r = 0; r < 4; ++r) {
                    gpre[r * 2 + 0] = *(const float4*)(gb + ((size_t)r << 10));
                    gpre[r * 2 + 1] = *(const float4*)(gb + ((size_t)r << 10) + 128);
                }
                e2a = *(const float4*)(e2 + kbase + ct * 4);
                e2b = *(const float4*)(e2 + kbase + 128 + ct * 4);
            }

            // compute: per d, 3 ds_read_b128 feed 32 FMAs
            const float* esp = &es[buf][0][0];
            const int xb = dc * 16;
            #pragma unroll
            for (int d = 0; d < 16; ++d) {
                const float4 xv = *(const float4*)&xs[xb + d][rt * 4];           // broadcast
                const float4 ea = *(const float4*)(esp + d * 264 + ct * 4);      // contiguous
                const float4 eb = *(const float4*)(esp + d * 264 + 128 + ct * 4);
                const float xr[4] = {xv.x, xv.y, xv.z, xv.w};
                const float ev[8] = {ea.x, ea.y, ea.z, ea.w, eb.x, eb.y, eb.z, eb.w};
                #pragma unroll
                for (int r = 0; r < 4; ++r)
                    #pragma unroll
                    for (int j = 0; j < 8; ++j)
                        acc[r][j] = fmaf(xr[r], ev[j], acc[r][j]);
            }
        }

        // ---- epilogue for these 256 cols: distances, gumbel argmax, KLD
        #pragma unroll
        for (int r = 0; r < 4; ++r) {
            const int row = rt * 4 + r;
            const float xn = xn2[row];
            #pragma unroll
            for (int q = 0; q < 2; ++q) {
                const float4 gv  = gpre[r * 2 + q];
                const float4 ev2 = q ? e2b : e2a;
                const int colb = kbase + q * 128 + ct * 4;
                const float gvp[4] = {gv.x, gv.y, gv.z, gv.w};
                const float e2p[4] = {ev2.x, ev2.y, ev2.z, ev2.w};
                #pragma unroll
                for (int j = 0; j < 4; ++j) {
                    float dist = xn + e2p[j] - 2.f * acc[r][q * 4 + j];
                    float val  = gvp[j] - dist;
                    if (val > runval[r]) { runval[r] = val; runidx[r] = colb + j; } // cols ascend
                    float p = 1.f / (1.f + __expf(dist));
                    kld_acc += p * __logf(fmaxf(p, 1e-8f));
                }
            }
        }
    }

    // ---- argmax reduce across the 32 col-lanes (first-index tie-break)
    #pragma unroll
    for (int r = 0; r < 4; ++r) {
        float v = runval[r];
        int   c = runidx[r];
        #pragma unroll
        for (int off = 16; off > 0; off >>= 1) {
            float ov = __shfl_xor(v, off, 32);
            int   oc = __shfl_xor(c, off, 32);
            if (ov > v || (ov == v && oc < c)) { v = ov; c = oc; }
        }
        if (ct == 0) {
            idxs[rt * 4 + r] = c;
            atomicAdd(&counts[c], 1.0f);
        }
    }
    __syncthreads();

    // ---- encodings: one-hot, fully coalesced float4 stores
    {
        float* enc = out + ENC_OFF;
        for (int t = tid; t < BM * (KCODES / 4); t += 256) {
            int c4 = t & 255, row = t >> 8;
            int base = c4 * 4;
            int id = idxs[row];
            float4 v;
            v.x = (base + 0 == id) ? 1.f : 0.f;
            v.y = (base + 1 == id) ? 1.f : 0.f;
            v.z = (base + 2 == id) ? 1.f : 0.f;
            v.w = (base + 3 == id) ? 1.f : 0.f;
            *(float4*)(enc + ((size_t)(n0 + row) << 10) + base) = v;
        }
    }

    // ---- quantized gather + store (NCHW) + e_latent partial
    float elat_acc = 0.f;
    {
        float* outq = out + QUANT_OFF;
        for (int t = tid; t < DDIM * (BM / 4); t += 256) {  // (c, r4)
            int r4 = t & 7, c = t >> 3;
            float4 xv = *(const float4*)&xs[c][r4 * 4];
            float q0 = emb[(size_t)idxs[r4 * 4 + 0] * DDIM + c];
            float q1 = emb[(size_t)idxs[r4 * 4 + 1] * DDIM + c];
            float q2 = emb[(size_t)idxs[r4 * 4 + 2] * DDIM + c];
            float q3 = emb[(size_t)idxs[r4 * 4 + 3] * DDIM + c];
            float d0 = q0 - xv.x, d1 = q1 - xv.y, d2 = q2 - xv.z, d3 = q3 - xv.w;
            elat_acc = fmaf(d0, d0, elat_acc);
            elat_acc = fmaf(d1, d1, elat_acc);
            elat_acc = fmaf(d2, d2, elat_acc);
            elat_acc = fmaf(d3, d3, elat_acc);
            float4 qv = make_float4(q0, q1, q2, q3);
            *(float4*)(outq + (((size_t)(b * DDIM + c)) << 10) + s0 + r4 * 4) = qv;
        }
    }

    // ---- block-reduce kld & elat, one atomic each per block
    #pragma unroll
    for (int off = 32; off > 0; off >>= 1) {
        kld_acc  += __shfl_xor(kld_acc, off);
        elat_acc += __shfl_xor(elat_acc, off);
    }
    int wave = tid >> 6;
    if ((tid & 63) == 0) { redK[wave] = kld_acc; redE[wave] = elat_acc; }
    __syncthreads();
    if (tid == 0) {
        atomicAdd(&ws[2 * KCODES],     redK[0] + redK[1] + redK[2] + redK[3]);
        atomicAdd(&ws[2 * KCODES + 1], redE[0] + redE[1] + redE[2] + redE[3]);
    }
}

__global__ void __launch_bounds__(256)
vq_finalize(const float* __restrict__ ws, float* __restrict__ out) {
    __shared__ float red[4];
    int tid = threadIdx.x;
    float s = 0.f;
    for (int k = tid; k < KCODES; k += 256) {
        float avg = ws[KCODES + k] * (1.f / (float)NROWS);
        s += avg * logf(avg + 1e-10f);
    }
    #pragma unroll
    for (int off = 32; off > 0; off >>= 1) s += __shfl_xor(s, off);
    if ((tid & 63) == 0) red[tid >> 6] = s;
    __syncthreads();
    if (tid == 0) {
        float ssum = red[0] + red[1] + red[2] + red[3];
        float perp = expf(-ssum);
        float kld  = ws[2 * KCODES]     / (float)NROWS;
        float elat = ws[2 * KCODES + 1] / (float)(NROWS * DDIM);
        float ratio = kld / fmaxf(elat, 1e-8f);
        float loss  = 1.5f * (kld + elat * ratio);
        out[0]        = loss;
        out[PERP_OFF] = perp;
    }
}

extern "C" void kernel_launch(void* const* d_in, const int* in_sizes, int n_in,
                              void* d_out, int out_size, void* d_ws, size_t ws_size,
                              hipStream_t stream) {
    const float* inp = (const float*)d_in[0];   // [32,256,32,32]
    const float* emb = (const float*)d_in[1];   // [1024,256]
    const float* gmb = (const float*)d_in[2];   // [32768,1024]
    float* out = (float*)d_out;
    float* ws  = (float*)d_ws;

    vq_setup<<<dim3(KCODES / 256), dim3(256), 0, stream>>>(emb, ws);
    vq_main<<<dim3(NROWS / BM), dim3(256), 0, stream>>>(inp, emb, gmb, out, ws);
    vq_finalize<<<dim3(1), dim3(256), 0, stream>>>(ws, out);
}